// Round 5
// baseline (320.971 us; speedup 1.0000x reference)
//
#include <hip/hip_runtime.h>
#include <hip/hip_bf16.h>

#define N_NODES 100000
#define N_EDGES 1600000
#define IN_FEA 128
#define HIDDEN 128
#define RANK 64

#define NBUCK 391          // ceil(N_NODES/256): bucket b = nodes [b*256, b*256+256)
#define C_BLOCKS 1024      // hist blocks
#define EPB 1563           // edges per hist block
#define S_BLOCKS 128       // binscatter blocks (chunk = 8 hist rows)
#define CHUNK_W (EPB * 8)  // 12504 edges per scatter chunk
#define GEMM1_BLOCKS 1563  // ceil(N_NODES / 64)

#define AGG_BLOCKS 1563    // ceil(N_NODES / 64): 64 nodes per 512-thread block

// ---------------- helpers ----------------

__device__ __forceinline__ void fma4(float4& a, float s, const float4& b) {
    a.x = fmaf(s, b.x, a.x);
    a.y = fmaf(s, b.y, a.y);
    a.z = fmaf(s, b.z, a.z);
    a.w = fmaf(s, b.w, a.w);
}

__device__ __forceinline__ unsigned short f2bf_rne(float f) {
    unsigned u = __float_as_uint(f);
    u += 0x7fffu + ((u >> 16) & 1u);
    return (unsigned short)(u >> 16);
}

// low bf16 of a packed uint -> float (1 VALU: lshl)
__device__ __forceinline__ float bfu_lo(unsigned u) {
    return __uint_as_float(u << 16);
}
// high bf16 of a packed uint -> float (1 VALU: and)
__device__ __forceinline__ float bfu_hi(unsigned u) {
    return __uint_as_float(u & 0xffff0000u);
}

// ---------------- fused GEMM1 + bucket histogram ----------------
// blocks [0, GEMM1_BLOCKS): h_bf = bf16(x @ W), 64 nodes/block.
// blocks [GEMM1_BLOCKS, +C_BLOCKS): per-block bucket histogram (EPB edges each).

__global__ __launch_bounds__(256) void gemm1_hist_kernel(const float* __restrict__ x,
                                                         const float* __restrict__ W,
                                                         unsigned short* __restrict__ hb,
                                                         const int* __restrict__ dst,
                                                         int* __restrict__ bhist,
                                                         int* __restrict__ blockhist) {
    __shared__ float Wl[IN_FEA * RANK];  // 32 KB (hist aliases first 1.6 KB)
    int t = threadIdx.x;

    if (blockIdx.x >= GEMM1_BLOCKS) {
        int* hist = (int*)Wl;
        int b = blockIdx.x - GEMM1_BLOCKS;
        for (int i = t; i < NBUCK; i += 256) hist[i] = 0;
        __syncthreads();
        int b0 = b * EPB;
        int b1 = min(b0 + EPB, N_EDGES);
        for (int e = b0 + t; e < b1; e += 256)
            atomicAdd(&hist[dst[e] >> 8], 1);
        __syncthreads();
        for (int i = t; i < NBUCK; i += 256) {
            int c = hist[i];
            blockhist[b * NBUCK + i] = c;
            if (c) atomicAdd(&bhist[i], c);
        }
        return;
    }

    for (int i = t; i < IN_FEA * RANK; i += 256) Wl[i] = W[i];
    __syncthreads();

    int r0 = (t & 15) * 4;
    int n0 = blockIdx.x * 64 + (t >> 4) * 4;
    const float4* x0 = (const float4*)(x + (long)min(n0 + 0, N_NODES - 1) * IN_FEA);
    const float4* x1 = (const float4*)(x + (long)min(n0 + 1, N_NODES - 1) * IN_FEA);
    const float4* x2 = (const float4*)(x + (long)min(n0 + 2, N_NODES - 1) * IN_FEA);
    const float4* x3 = (const float4*)(x + (long)min(n0 + 3, N_NODES - 1) * IN_FEA);
    float4 a0 = {0.f, 0.f, 0.f, 0.f}, a1 = a0, a2 = a0, a3 = a0;
    for (int k4 = 0; k4 < IN_FEA / 4; ++k4) {
        float4 v0 = x0[k4], v1 = x1[k4], v2 = x2[k4], v3 = x3[k4];
        int kb = k4 * 4;
        float4 w0 = *(const float4*)&Wl[(kb + 0) * RANK + r0];
        float4 w1 = *(const float4*)&Wl[(kb + 1) * RANK + r0];
        float4 w2 = *(const float4*)&Wl[(kb + 2) * RANK + r0];
        float4 w3 = *(const float4*)&Wl[(kb + 3) * RANK + r0];
        fma4(a0, v0.x, w0); fma4(a0, v0.y, w1); fma4(a0, v0.z, w2); fma4(a0, v0.w, w3);
        fma4(a1, v1.x, w0); fma4(a1, v1.y, w1); fma4(a1, v1.z, w2); fma4(a1, v1.w, w3);
        fma4(a2, v2.x, w0); fma4(a2, v2.y, w1); fma4(a2, v2.z, w2); fma4(a2, v2.w, w3);
        fma4(a3, v3.x, w0); fma4(a3, v3.y, w1); fma4(a3, v3.z, w2); fma4(a3, v3.w, w3);
    }
    float4 accs[4] = {a0, a1, a2, a3};
#pragma unroll
    for (int i = 0; i < 4; ++i) {
        if (n0 + i < N_NODES) {
            ushort4 o;
            o.x = f2bf_rne(accs[i].x); o.y = f2bf_rne(accs[i].y);
            o.z = f2bf_rne(accs[i].z); o.w = f2bf_rne(accs[i].w);
            *(ushort4*)(hb + (n0 + i) * RANK + r0) = o;
        }
    }
}

// ---------------- CSR build (rest) ----------------

__global__ void bucket_scan_kernel(const int* __restrict__ bhist,
                                   int* __restrict__ bucket_offs,
                                   int* __restrict__ bucket_cursor,
                                   int* __restrict__ offs) {
    __shared__ int sd[512];
    int t = threadIdx.x;
    int v = (t < NBUCK) ? bhist[t] : 0;
    sd[t] = v;
    __syncthreads();
    for (int off = 1; off < 512; off <<= 1) {
        int a = 0;
        if (t >= off) a = sd[t - off];
        __syncthreads();
        sd[t] += a;
        __syncthreads();
    }
    if (t < NBUCK) {
        int excl = sd[t] - v;
        bucket_offs[t] = excl;
        bucket_cursor[t] = excl;
    }
    if (t == 0) {
        bucket_offs[NBUCK] = N_EDGES;
        offs[N_NODES] = N_EDGES;
    }
}

// Fat-chunk scatter: 128 blocks x 1024 threads, one read pass. Per (block,bucket)
// run length ~= 12504/391 ~= 32 edges = 128 B -> mostly full-line writebacks
// (kills the partial-line write amplification + RFO fetches of the 1024-block form).
__global__ __launch_bounds__(1024) void binscatter_kernel(const int* __restrict__ src,
                                                          const int* __restrict__ dst,
                                                          const int* __restrict__ blockhist,
                                                          int* __restrict__ bucket_cursor,
                                                          unsigned* __restrict__ pairs) {
    __shared__ int wbase[NBUCK];
    __shared__ int cur[NBUCK];
    int t = threadIdx.x;
    int b = blockIdx.x;
    if (t < NBUCK) {
        int s = 0;
#pragma unroll
        for (int k = 0; k < 8; ++k)
            s += blockhist[(8 * b + k) * NBUCK + t];
        wbase[t] = s ? atomicAdd(&bucket_cursor[t], s) : 0;
        cur[t] = 0;
    }
    __syncthreads();
    int e0 = b * CHUNK_W;
    int e1 = min(e0 + CHUNK_W, N_EDGES);
    for (int e = e0 + t; e < e1; e += 1024) {
        int d = dst[e];
        int s = src[e];
        int bk = d >> 8;
        int lp = atomicAdd(&cur[bk], 1);
        pairs[wbase[bk] + lp] = ((unsigned)s << 8) | (unsigned)(d & 255);
    }
}

__global__ __launch_bounds__(256) void bucket_build_kernel(const unsigned* __restrict__ pairs,
                                                           const int* __restrict__ bucket_offs,
                                                           int* __restrict__ offs,
                                                           int* __restrict__ eidx) {
    __shared__ int dcnt[256];
    __shared__ int sd[256];
    __shared__ int cur[256];
    int b = blockIdx.x, t = threadIdx.x;
    int base = bucket_offs[b], end = bucket_offs[b + 1];
    dcnt[t] = 0;
    __syncthreads();
    for (int i = base + t; i < end; i += 256)
        atomicAdd(&dcnt[pairs[i] & 255u], 1);
    __syncthreads();
    int v = dcnt[t];
    sd[t] = v;
    __syncthreads();
    for (int off = 1; off < 256; off <<= 1) {
        int a = 0;
        if (t >= off) a = sd[t - off];
        __syncthreads();
        sd[t] += a;
        __syncthreads();
    }
    int excl = sd[t] - v;
    int node = b * 256 + t;
    if (node < N_NODES) offs[node] = base + excl;
    cur[t] = excl;
    __syncthreads();
    for (int i = base + t; i < end; i += 256) {
        unsigned r = pairs[i];
        int lp = atomicAdd(&cur[r & 255u], 1);
        eidx[base + lp] = (int)(r >> 8);
    }
}

// ---------------- fused aggregation + GEMM2 ----------------
// The V-in-LDS epilogue is LDS-RETURN-BW-bound: a broadcast ds_read_b128 costs
// the same return-path time as a distinct-address read (1024 B/instr to VGPRs),
// so V-broadcast-p structures floor at ~45 us (16 + 32/NPW b128 reads/node).
// Fix: SCALAR-V epilogue. 512-thread blocks, 64 nodes/block:
//  - edge-product phase: 8 nodes/wave sequential (rolled loop + sched_barrier
//    to prevent the R10 cross-node fusion spill), p -> pls[64][68].
//  - transpose: lane l reads node (base+l)'s full 64-float p into 16 float4s
//    (stride 68 -> 8 lanes span all 32 banks, minimum-clean).
//  - V via SCALAR loads: wave w (readfirstlane-hoisted) covers h in
//    [16w,16w+16); V[h*64+r] with uniform indices -> s_load through sK$.
//    v_fmac with SGPR operand: zero LDS / zero VMEM for V.
//  - coalesced store via outbuf[64][132] staging (direct stores would be a
//    64-line scatter per instr).
// LDS traffic 3.3 GB -> ~0.35 GB; epilogue becomes VALU-bound (~11 us FMA).
// (R13 = resubmission of R12: container-level failure, no kernel fault
//  evidence; full bounds/alignment audit clean.)

__global__ __launch_bounds__(512, 4) void agg_gemm_kernel(const unsigned short* __restrict__ hb,
                                                          const float* __restrict__ norm,
                                                          const float* __restrict__ V,
                                                          const int* __restrict__ offs,
                                                          const int* __restrict__ eidx,
                                                          float* __restrict__ out) {
    __shared__ float pls[64 * 68];      // 17,408 B: p vectors, pad-68 rows
    __shared__ float outbuf[64 * 132];  // 33,792 B: out staging, pad-132 rows
    int t = threadIdx.x;
    int w = t >> 6, lane = t & 63;
    int half = lane >> 5;      // which edge of the pair this lane serves
    int l32 = lane & 31;       // rank-pair index: ranks {2*l32, 2*l32+1}
    int base = blockIdx.x * 64;
    const unsigned* hb2 = (const unsigned*)hb;  // hb2[s*32 + l32] = packed ranks {2*l32, 2*l32+1}

    // ---- edge-product phase: 8 nodes per wave, sequential ----
#pragma clang loop unroll(disable)
    for (int i = 0; i < 8; ++i) {
        int node = base + w * 8 + i;
        int beg = 0, end = 0;
        if (node < N_NODES) { beg = offs[node]; end = offs[node + 1]; }

        float plo = 1.0f, phi = 1.0f;
        for (int c = beg; c < end; c += 64) {
            int n = min(64, end - c);
            int sidx = (c + lane < end) ? eidx[c + lane] : 0;
            int j = 0;
            // 8 loads in flight = 16 edges
            for (; j + 16 <= n; j += 16) {
                int s0 = __shfl(sidx, j + 0  + half);
                int s1 = __shfl(sidx, j + 2  + half);
                int s2 = __shfl(sidx, j + 4  + half);
                int s3 = __shfl(sidx, j + 6  + half);
                int s4 = __shfl(sidx, j + 8  + half);
                int s5 = __shfl(sidx, j + 10 + half);
                int s6 = __shfl(sidx, j + 12 + half);
                int s7 = __shfl(sidx, j + 14 + half);
                unsigned u0 = hb2[(s0 << 5) | l32];
                unsigned u1 = hb2[(s1 << 5) | l32];
                unsigned u2 = hb2[(s2 << 5) | l32];
                unsigned u3 = hb2[(s3 << 5) | l32];
                unsigned u4 = hb2[(s4 << 5) | l32];
                unsigned u5 = hb2[(s5 << 5) | l32];
                unsigned u6 = hb2[(s6 << 5) | l32];
                unsigned u7 = hb2[(s7 << 5) | l32];
                plo *= ((bfu_lo(u0) * bfu_lo(u1)) * (bfu_lo(u2) * bfu_lo(u3))) *
                       ((bfu_lo(u4) * bfu_lo(u5)) * (bfu_lo(u6) * bfu_lo(u7)));
                phi *= ((bfu_hi(u0) * bfu_hi(u1)) * (bfu_hi(u2) * bfu_hi(u3))) *
                       ((bfu_hi(u4) * bfu_hi(u5)) * (bfu_hi(u6) * bfu_hi(u7)));
            }
            // 4 loads = 8 edges
            for (; j + 8 <= n; j += 8) {
                int s0 = __shfl(sidx, j + 0 + half);
                int s1 = __shfl(sidx, j + 2 + half);
                int s2 = __shfl(sidx, j + 4 + half);
                int s3 = __shfl(sidx, j + 6 + half);
                unsigned u0 = hb2[(s0 << 5) | l32];
                unsigned u1 = hb2[(s1 << 5) | l32];
                unsigned u2 = hb2[(s2 << 5) | l32];
                unsigned u3 = hb2[(s3 << 5) | l32];
                plo *= (bfu_lo(u0) * bfu_lo(u1)) * (bfu_lo(u2) * bfu_lo(u3));
                phi *= (bfu_hi(u0) * bfu_hi(u1)) * (bfu_hi(u2) * bfu_hi(u3));
            }
            // pair tail (2 edges / iter; odd edge masked to identity on upper half)
            for (; j < n; j += 2) {
                int jj = j + half;                 // jj <= n <= 64; lane n has sidx=0 -> safe addr
                int s = __shfl(sidx, jj);
                unsigned u = hb2[(s << 5) | l32];
                float alo = bfu_lo(u), ahi = bfu_hi(u);
                if (jj >= n) { alo = 1.0f; ahi = 1.0f; }
                plo *= alo;
                phi *= ahi;
            }
        }
        // merge edge-parity halves: lane l and lane l^32 hold the same rank pair
        plo *= __shfl_xor(plo, 32);
        phi *= __shfl_xor(phi, 32);

        if (lane < 32) {
            float nrm = (node < N_NODES) ? norm[node] : 0.f;
            float2 o;
            o.x = plo * nrm;
            o.y = phi * nrm;
            *(float2*)&pls[(w * 8 + i) * 68 + l32 * 2] = o;
        }
        __builtin_amdgcn_sched_barrier(0);  // keep node iterations separate (no fusion spill)
    }
    __syncthreads();

    // ---- transpose: lane l holds node (base+l)'s full p vector ----
    float4 p4[16];
#pragma unroll
    for (int q = 0; q < 16; ++q)
        p4[q] = *(const float4*)&pls[lane * 68 + q * 4];

    // ---- scalar-V GEMM2: wave w covers h in [16w, 16w+16) ----
    int w_u = __builtin_amdgcn_readfirstlane(w);
    const float* Vw = V + w_u * 16 * RANK;
    float acc[16];
#pragma unroll
    for (int h0 = 0; h0 < 16; ++h0) {
        const float* Vh = Vw + h0 * RANK;   // uniform -> s_load
        float ax = 0.f, ay = 0.f, az = 0.f, aw = 0.f;
#pragma unroll
        for (int q = 0; q < 16; ++q) {
            ax = fmaf(Vh[4 * q + 0], p4[q].x, ax);
            ay = fmaf(Vh[4 * q + 1], p4[q].y, ay);
            az = fmaf(Vh[4 * q + 2], p4[q].z, az);
            aw = fmaf(Vh[4 * q + 3], p4[q].w, aw);
        }
        acc[h0] = (ax + ay) + (az + aw);
    }

    // ---- stage to LDS, then coalesced store ----
#pragma unroll
    for (int k = 0; k < 4; ++k) {
        float4 o = {acc[4 * k + 0], acc[4 * k + 1], acc[4 * k + 2], acc[4 * k + 3]};
        *(float4*)&outbuf[lane * 132 + w * 16 + 4 * k] = o;
    }
    __syncthreads();
#pragma unroll
    for (int m = 0; m < 4; ++m) {
        int idx4 = m * 512 + t;            // 0..2047 float4 slots (64 rows x 32)
        int row = idx4 >> 5;
        int col4 = idx4 & 31;
        int node = base + row;
        if (node < N_NODES) {
            float4 v = *(const float4*)&outbuf[row * 132 + col4 * 4];
            *(float4*)&out[node * HIDDEN + col4 * 4] = v;
        }
    }
}

// ---------------- launch ----------------

extern "C" void kernel_launch(void* const* d_in, const int* in_sizes, int n_in,
                              void* d_out, int out_size, void* d_ws, size_t ws_size,
                              hipStream_t stream) {
    const float* x    = (const float*)d_in[0];
    const float* norm = (const float*)d_in[1];
    const float* W    = (const float*)d_in[2];
    const float* V    = (const float*)d_in[3];
    const int*   src  = (const int*)d_in[4];
    const int*   dst  = (const int*)d_in[5];
    float* out = (float*)d_out;

    // workspace layout (ws): hb (bf16), offs, eidx, small bucket arrays
    unsigned short* hb = (unsigned short*)d_ws;              // N*RANK bf16 (12.8 MB)
    int*   offs        = (int*)(hb + (long)N_NODES * RANK);  // N+1
    int*   eidx        = offs + N_NODES + 1;                 // E
    int*   bhist       = eidx + N_EDGES;                     // NBUCK
    int*   bucket_offs = bhist + NBUCK;                      // NBUCK+1
    int*   bucket_cur  = bucket_offs + NBUCK + 1;            // NBUCK

    // scratch inside d_out (dead until agg_gemm writes out):
    unsigned* pairs    = (unsigned*)d_out;                   // E uint32 (6.4 MB)
    int*     blockhist = (int*)d_out + 2097152;              // at +8 MB: C_BLOCKS*NBUCK ints (1.6 MB)

    hipMemsetAsync(bhist, 0, NBUCK * sizeof(int), stream);
    gemm1_hist_kernel<<<GEMM1_BLOCKS + C_BLOCKS, 256, 0, stream>>>(x, W, hb, dst, bhist, blockhist);
    bucket_scan_kernel<<<1, 512, 0, stream>>>(bhist, bucket_offs, bucket_cur, offs);
    binscatter_kernel<<<S_BLOCKS, 1024, 0, stream>>>(src, dst, blockhist, bucket_cur, pairs);
    bucket_build_kernel<<<NBUCK, 256, 0, stream>>>(pairs, bucket_offs, offs, eidx);
    agg_gemm_kernel<<<AGG_BLOCKS, 512, 0, stream>>>(hb, norm, V, offs, eidx, out);
}

// Round 6
// 309.587 us; speedup vs baseline: 1.0368x; 1.0368x over previous
//
#include <hip/hip_runtime.h>
#include <hip/hip_bf16.h>

#define N_NODES 100000
#define N_EDGES 1600000
#define IN_FEA 128
#define HIDDEN 128
#define RANK 64

#define NBUCK 391          // ceil(N_NODES/256): bucket b = nodes [b*256, b*256+256)
#define C_BLOCKS 1024      // hist blocks
#define EPB 1563           // edges per hist block
#define S_BLOCKS 128       // binscatter blocks (chunk = 8 hist rows)
#define CHUNK_W (EPB * 8)  // 12504 edges per scatter chunk
#define GEMM1_BLOCKS 1563  // ceil(N_NODES / 64)

#define AGG_BLOCKS 6250    // N_NODES / 16: one node per wave (R9 proven shape)
#define G2_BLOCKS 1250     // gemm2: 1250 x 4 waves x 20 nodes = 100000 exactly
#define G2_NPW 20

// ---------------- helpers ----------------

__device__ __forceinline__ void fma4(float4& a, float s, const float4& b) {
    a.x = fmaf(s, b.x, a.x);
    a.y = fmaf(s, b.y, a.y);
    a.z = fmaf(s, b.z, a.z);
    a.w = fmaf(s, b.w, a.w);
}

__device__ __forceinline__ unsigned short f2bf_rne(float f) {
    unsigned u = __float_as_uint(f);
    u += 0x7fffu + ((u >> 16) & 1u);
    return (unsigned short)(u >> 16);
}

// low bf16 of a packed uint -> float (1 VALU: lshl)
__device__ __forceinline__ float bfu_lo(unsigned u) {
    return __uint_as_float(u << 16);
}
// high bf16 of a packed uint -> float (1 VALU: and)
__device__ __forceinline__ float bfu_hi(unsigned u) {
    return __uint_as_float(u & 0xffff0000u);
}

// ---------------- fused GEMM1 + bucket histogram ----------------
// blocks [0, GEMM1_BLOCKS): h_bf = bf16(x @ W), 64 nodes/block.
// blocks [GEMM1_BLOCKS, +C_BLOCKS): per-block bucket histogram (EPB edges each).

__global__ __launch_bounds__(256) void gemm1_hist_kernel(const float* __restrict__ x,
                                                         const float* __restrict__ W,
                                                         unsigned short* __restrict__ hb,
                                                         const int* __restrict__ dst,
                                                         int* __restrict__ bhist,
                                                         int* __restrict__ blockhist) {
    __shared__ float Wl[IN_FEA * RANK];  // 32 KB (hist aliases first 1.6 KB)
    int t = threadIdx.x;

    if (blockIdx.x >= GEMM1_BLOCKS) {
        int* hist = (int*)Wl;
        int b = blockIdx.x - GEMM1_BLOCKS;
        for (int i = t; i < NBUCK; i += 256) hist[i] = 0;
        __syncthreads();
        int b0 = b * EPB;
        int b1 = min(b0 + EPB, N_EDGES);
        for (int e = b0 + t; e < b1; e += 256)
            atomicAdd(&hist[dst[e] >> 8], 1);
        __syncthreads();
        for (int i = t; i < NBUCK; i += 256) {
            int c = hist[i];
            blockhist[b * NBUCK + i] = c;
            if (c) atomicAdd(&bhist[i], c);
        }
        return;
    }

    for (int i = t; i < IN_FEA * RANK; i += 256) Wl[i] = W[i];
    __syncthreads();

    int r0 = (t & 15) * 4;
    int n0 = blockIdx.x * 64 + (t >> 4) * 4;
    const float4* x0 = (const float4*)(x + (long)min(n0 + 0, N_NODES - 1) * IN_FEA);
    const float4* x1 = (const float4*)(x + (long)min(n0 + 1, N_NODES - 1) * IN_FEA);
    const float4* x2 = (const float4*)(x + (long)min(n0 + 2, N_NODES - 1) * IN_FEA);
    const float4* x3 = (const float4*)(x + (long)min(n0 + 3, N_NODES - 1) * IN_FEA);
    float4 a0 = {0.f, 0.f, 0.f, 0.f}, a1 = a0, a2 = a0, a3 = a0;
    for (int k4 = 0; k4 < IN_FEA / 4; ++k4) {
        float4 v0 = x0[k4], v1 = x1[k4], v2 = x2[k4], v3 = x3[k4];
        int kb = k4 * 4;
        float4 w0 = *(const float4*)&Wl[(kb + 0) * RANK + r0];
        float4 w1 = *(const float4*)&Wl[(kb + 1) * RANK + r0];
        float4 w2 = *(const float4*)&Wl[(kb + 2) * RANK + r0];
        float4 w3 = *(const float4*)&Wl[(kb + 3) * RANK + r0];
        fma4(a0, v0.x, w0); fma4(a0, v0.y, w1); fma4(a0, v0.z, w2); fma4(a0, v0.w, w3);
        fma4(a1, v1.x, w0); fma4(a1, v1.y, w1); fma4(a1, v1.z, w2); fma4(a1, v1.w, w3);
        fma4(a2, v2.x, w0); fma4(a2, v2.y, w1); fma4(a2, v2.z, w2); fma4(a2, v2.w, w3);
        fma4(a3, v3.x, w0); fma4(a3, v3.y, w1); fma4(a3, v3.z, w2); fma4(a3, v3.w, w3);
    }
    float4 accs[4] = {a0, a1, a2, a3};
#pragma unroll
    for (int i = 0; i < 4; ++i) {
        if (n0 + i < N_NODES) {
            ushort4 o;
            o.x = f2bf_rne(accs[i].x); o.y = f2bf_rne(accs[i].y);
            o.z = f2bf_rne(accs[i].z); o.w = f2bf_rne(accs[i].w);
            *(ushort4*)(hb + (n0 + i) * RANK + r0) = o;
        }
    }
}

// ---------------- CSR build (rest) ----------------

__global__ void bucket_scan_kernel(const int* __restrict__ bhist,
                                   int* __restrict__ bucket_offs,
                                   int* __restrict__ bucket_cursor,
                                   int* __restrict__ offs) {
    __shared__ int sd[512];
    int t = threadIdx.x;
    int v = (t < NBUCK) ? bhist[t] : 0;
    sd[t] = v;
    __syncthreads();
    for (int off = 1; off < 512; off <<= 1) {
        int a = 0;
        if (t >= off) a = sd[t - off];
        __syncthreads();
        sd[t] += a;
        __syncthreads();
    }
    if (t < NBUCK) {
        int excl = sd[t] - v;
        bucket_offs[t] = excl;
        bucket_cursor[t] = excl;
    }
    if (t == 0) {
        bucket_offs[NBUCK] = N_EDGES;
        offs[N_NODES] = N_EDGES;
    }
}

// Fat-chunk scatter: 128 blocks x 1024 threads, one read pass. Per (block,bucket)
// run length ~= 12504/391 ~= 32 edges = 128 B -> mostly full-line writebacks
// (kills the partial-line write amplification + RFO fetches of the 1024-block form).
__global__ __launch_bounds__(1024) void binscatter_kernel(const int* __restrict__ src,
                                                          const int* __restrict__ dst,
                                                          const int* __restrict__ blockhist,
                                                          int* __restrict__ bucket_cursor,
                                                          unsigned* __restrict__ pairs) {
    __shared__ int wbase[NBUCK];
    __shared__ int cur[NBUCK];
    int t = threadIdx.x;
    int b = blockIdx.x;
    if (t < NBUCK) {
        int s = 0;
#pragma unroll
        for (int k = 0; k < 8; ++k)
            s += blockhist[(8 * b + k) * NBUCK + t];
        wbase[t] = s ? atomicAdd(&bucket_cursor[t], s) : 0;
        cur[t] = 0;
    }
    __syncthreads();
    int e0 = b * CHUNK_W;
    int e1 = min(e0 + CHUNK_W, N_EDGES);
    for (int e = e0 + t; e < e1; e += 1024) {
        int d = dst[e];
        int s = src[e];
        int bk = d >> 8;
        int lp = atomicAdd(&cur[bk], 1);
        pairs[wbase[bk] + lp] = ((unsigned)s << 8) | (unsigned)(d & 255);
    }
}

__global__ __launch_bounds__(256) void bucket_build_kernel(const unsigned* __restrict__ pairs,
                                                           const int* __restrict__ bucket_offs,
                                                           int* __restrict__ offs,
                                                           int* __restrict__ eidx) {
    __shared__ int dcnt[256];
    __shared__ int sd[256];
    __shared__ int cur[256];
    int b = blockIdx.x, t = threadIdx.x;
    int base = bucket_offs[b], end = bucket_offs[b + 1];
    dcnt[t] = 0;
    __syncthreads();
    for (int i = base + t; i < end; i += 256)
        atomicAdd(&dcnt[pairs[i] & 255u], 1);
    __syncthreads();
    int v = dcnt[t];
    sd[t] = v;
    __syncthreads();
    for (int off = 1; off < 256; off <<= 1) {
        int a = 0;
        if (t >= off) a = sd[t - off];
        __syncthreads();
        sd[t] += a;
        __syncthreads();
    }
    int excl = sd[t] - v;
    int node = b * 256 + t;
    if (node < N_NODES) offs[node] = base + excl;
    cur[t] = excl;
    __syncthreads();
    for (int i = base + t; i < end; i += 256) {
        unsigned r = pairs[i];
        int lp = atomicAdd(&cur[r & 255u], 1);
        eidx[base + lp] = (int)(r >> 8);
    }
}

// ---------------- aggregation (gather + product only) ----------------
// R14: DE-FUSE. The fused epilogue forced one register/occupancy config onto
// two phases with opposite needs (R12's scalar-V fusion: occupancy 35%, 131 us;
// R11's LDS-V fusion: LDS-return-BW floor ~45 us). Round-tripping p costs only
// ~8 us of HBM (25.6 MB write + read) and p lives IN out[n][0:64] (first 256 B
// of each 512 B row; gemm2 reads it and overwrites the same row in-place, same
// wave -> no race, zero extra workspace).
// This kernel: R9/R11 proven gather shape (1 node/wave, 16 waves, 6250 blocks,
// short-lived blocks retire in dispatch order -> L2-warm hb gathers), ZERO LDS,
// ~28 VGPR -> wave-slot-capped occupancy, max gather latency hiding.

__global__ __launch_bounds__(1024) void agg_kernel(const unsigned short* __restrict__ hb,
                                                   const float* __restrict__ norm,
                                                   const int* __restrict__ offs,
                                                   const int* __restrict__ eidx,
                                                   float* __restrict__ out) {
    int t = threadIdx.x;
    int wave = t >> 6, lane = t & 63;
    int half = lane >> 5;      // which edge of the pair this lane serves
    int l32 = lane & 31;       // rank-pair index: ranks {2*l32, 2*l32+1}
    int node = blockIdx.x * 16 + wave;
    int beg = offs[node], end = offs[node + 1];
    const unsigned* hb2 = (const unsigned*)hb;  // hb2[s*32 + l32] = packed ranks {2*l32, 2*l32+1}

    float plo = 1.0f, phi = 1.0f;
    for (int c = beg; c < end; c += 64) {
        int n = min(64, end - c);
        int sidx = (c + lane < end) ? eidx[c + lane] : 0;
        int j = 0;
        // 8 loads in flight = 16 edges
        for (; j + 16 <= n; j += 16) {
            int s0 = __shfl(sidx, j + 0  + half);
            int s1 = __shfl(sidx, j + 2  + half);
            int s2 = __shfl(sidx, j + 4  + half);
            int s3 = __shfl(sidx, j + 6  + half);
            int s4 = __shfl(sidx, j + 8  + half);
            int s5 = __shfl(sidx, j + 10 + half);
            int s6 = __shfl(sidx, j + 12 + half);
            int s7 = __shfl(sidx, j + 14 + half);
            unsigned u0 = hb2[(s0 << 5) | l32];
            unsigned u1 = hb2[(s1 << 5) | l32];
            unsigned u2 = hb2[(s2 << 5) | l32];
            unsigned u3 = hb2[(s3 << 5) | l32];
            unsigned u4 = hb2[(s4 << 5) | l32];
            unsigned u5 = hb2[(s5 << 5) | l32];
            unsigned u6 = hb2[(s6 << 5) | l32];
            unsigned u7 = hb2[(s7 << 5) | l32];
            plo *= ((bfu_lo(u0) * bfu_lo(u1)) * (bfu_lo(u2) * bfu_lo(u3))) *
                   ((bfu_lo(u4) * bfu_lo(u5)) * (bfu_lo(u6) * bfu_lo(u7)));
            phi *= ((bfu_hi(u0) * bfu_hi(u1)) * (bfu_hi(u2) * bfu_hi(u3))) *
                   ((bfu_hi(u4) * bfu_hi(u5)) * (bfu_hi(u6) * bfu_hi(u7)));
        }
        // 4 loads = 8 edges
        for (; j + 8 <= n; j += 8) {
            int s0 = __shfl(sidx, j + 0 + half);
            int s1 = __shfl(sidx, j + 2 + half);
            int s2 = __shfl(sidx, j + 4 + half);
            int s3 = __shfl(sidx, j + 6 + half);
            unsigned u0 = hb2[(s0 << 5) | l32];
            unsigned u1 = hb2[(s1 << 5) | l32];
            unsigned u2 = hb2[(s2 << 5) | l32];
            unsigned u3 = hb2[(s3 << 5) | l32];
            plo *= (bfu_lo(u0) * bfu_lo(u1)) * (bfu_lo(u2) * bfu_lo(u3));
            phi *= (bfu_hi(u0) * bfu_hi(u1)) * (bfu_hi(u2) * bfu_hi(u3));
        }
        // pair tail (2 edges / iter; odd edge masked to identity on upper half)
        for (; j < n; j += 2) {
            int jj = j + half;                 // jj <= n <= 64; lane n has sidx=0 -> safe addr
            int s = __shfl(sidx, jj);
            unsigned u = hb2[(s << 5) | l32];
            float alo = bfu_lo(u), ahi = bfu_hi(u);
            if (jj >= n) { alo = 1.0f; ahi = 1.0f; }
            plo *= alo;
            phi *= ahi;
        }
    }
    // merge edge-parity halves: lane l and lane l^32 hold the same rank pair
    plo *= __shfl_xor(plo, 32);
    phi *= __shfl_xor(phi, 32);

    if (lane < 32) {
        float nrm = norm[node];
        float2 o;
        o.x = plo * nrm;
        o.y = phi * nrm;
        // p[node] staged into out[node][0:64] (two full 128 B lines)
        *(float2*)&out[(long)node * HIDDEN + l32 * 2] = o;
    }
}

// ---------------- GEMM2 (in-place: out[n][0:64] = p -> out[n][0:128]) ----------------
// Streaming skinny GEMM at its own ideal config: V in VGPRs (lane l holds rows
// l and l+64 = 128 VGPRs, loaded once per wave from L2), p as wave-uniform
// scalar loads (readfirstlane-certified node -> s_load path, zero LDS, zero
// per-node vector loads), 128 v_fmac with SGPR operand per node per lane.
// In-place safety: the wave that reads row n's p is the only writer of row n,
// and its reads precede its writes in program order.
// Floor: 1.6 GFLOP fp32 = 10.4 us VALU; HBM 77 MB = 12 us.

__global__ __launch_bounds__(256) void gemm2_kernel(const float* __restrict__ V,
                                                    float* __restrict__ out) {
    int t = threadIdx.x, w = t >> 6, lane = t & 63;

    // V rows for this lane's two output columns (h = lane, h = lane+64)
    float4 va[16], vb[16];
    const float4* Va = (const float4*)(V + lane * RANK);
    const float4* Vb = (const float4*)(V + (lane + 64) * RANK);
#pragma unroll
    for (int q = 0; q < 16; ++q) { va[q] = Va[q]; vb[q] = Vb[q]; }

    int wid = __builtin_amdgcn_readfirstlane(blockIdx.x * 4 + w);
    int n0 = wid * G2_NPW;
#pragma clang loop unroll(disable)
    for (int i = 0; i < G2_NPW; ++i) {
        int node = n0 + i;                       // wave-uniform
        const float* pn = out + (long)node * HIDDEN;  // uniform addr -> scalar loads
        float a0 = 0.f, a1 = 0.f;
#pragma unroll
        for (int q = 0; q < 16; ++q) {
            float p0 = pn[4 * q + 0];
            float p1 = pn[4 * q + 1];
            float p2 = pn[4 * q + 2];
            float p3 = pn[4 * q + 3];
            a0 = fmaf(p0, va[q].x, a0);
            a1 = fmaf(p0, vb[q].x, a1);
            a0 = fmaf(p1, va[q].y, a0);
            a1 = fmaf(p1, vb[q].y, a1);
            a0 = fmaf(p2, va[q].z, a0);
            a1 = fmaf(p2, vb[q].z, a1);
            a0 = fmaf(p3, va[q].w, a0);
            a1 = fmaf(p3, vb[q].w, a1);
        }
        out[(long)node * HIDDEN + lane]      = a0;
        out[(long)node * HIDDEN + 64 + lane] = a1;
    }
}

// ---------------- launch ----------------

extern "C" void kernel_launch(void* const* d_in, const int* in_sizes, int n_in,
                              void* d_out, int out_size, void* d_ws, size_t ws_size,
                              hipStream_t stream) {
    const float* x    = (const float*)d_in[0];
    const float* norm = (const float*)d_in[1];
    const float* W    = (const float*)d_in[2];
    const float* V    = (const float*)d_in[3];
    const int*   src  = (const int*)d_in[4];
    const int*   dst  = (const int*)d_in[5];
    float* out = (float*)d_out;

    // workspace layout (ws): hb (bf16), offs, eidx, small bucket arrays
    unsigned short* hb = (unsigned short*)d_ws;              // N*RANK bf16 (12.8 MB)
    int*   offs        = (int*)(hb + (long)N_NODES * RANK);  // N+1
    int*   eidx        = offs + N_NODES + 1;                 // E
    int*   bhist       = eidx + N_EDGES;                     // NBUCK
    int*   bucket_offs = bhist + NBUCK;                      // NBUCK+1
    int*   bucket_cur  = bucket_offs + NBUCK + 1;            // NBUCK

    // scratch inside d_out (dead once consumed; agg/gemm2 then own the rows):
    unsigned* pairs    = (unsigned*)d_out;                   // E uint32 (6.4 MB)
    int*     blockhist = (int*)d_out + 2097152;              // at +8 MB: C_BLOCKS*NBUCK ints (1.6 MB)

    hipMemsetAsync(bhist, 0, NBUCK * sizeof(int), stream);
    gemm1_hist_kernel<<<GEMM1_BLOCKS + C_BLOCKS, 256, 0, stream>>>(x, W, hb, dst, bhist, blockhist);
    bucket_scan_kernel<<<1, 512, 0, stream>>>(bhist, bucket_offs, bucket_cur, offs);
    binscatter_kernel<<<S_BLOCKS, 1024, 0, stream>>>(src, dst, blockhist, bucket_cur, pairs);
    bucket_build_kernel<<<NBUCK, 256, 0, stream>>>(pairs, bucket_offs, offs, eidx);
    agg_kernel<<<AGG_BLOCKS, 1024, 0, stream>>>(hb, norm, offs, eidx, out);
    gemm2_kernel<<<G2_BLOCKS, 256, 0, stream>>>(V, out);
}